// Round 2
// baseline (40339.780 us; speedup 1.0000x reference)
//
#include <hip/hip_runtime.h>
#include <math.h>

#define CDIV(a,b) (((a)+(b)-1)/(b))

// ---------------- helpers ----------------
__device__ __forceinline__ float wsum(float v){
  #pragma unroll
  for (int o = 32; o; o >>= 1) v += __shfl_xor(v, o);
  return v;
}
__device__ __forceinline__ float wmaxr(float v){
  #pragma unroll
  for (int o = 32; o; o >>= 1) v = fmaxf(v, __shfl_xor(v, o));
  return v;
}
__device__ __forceinline__ float silu_f(float v){ return v / (1.f + expf(-v)); }

// ---------------- generic GEMM: C[M,N] = A[M,K] @ B[N,K]^T + bias ----------------
__global__ __launch_bounds__(256) void gemm_nt(
    const float* __restrict__ A, const float* __restrict__ B,
    const float* __restrict__ bias, float* __restrict__ C,
    int M, int N, int K, int lda, int ldb, int ldc)
{
  __shared__ float As[16][65];   // As[k][m]
  __shared__ float Bs[16][65];   // Bs[k][n]
  const int tid = threadIdx.x;
  const int tx = tid & 15, ty = tid >> 4;
  const int m0 = blockIdx.y * 64, n0 = blockIdx.x * 64;
  float acc[4][4] = {};
  for (int k0 = 0; k0 < K; k0 += 16) {
    #pragma unroll
    for (int i = tid; i < 1024; i += 256) {
      int k = i & 15, m = i >> 4;
      int gm = m0 + m, gk = k0 + k;
      As[k][m] = (gm < M && gk < K) ? A[(size_t)gm*lda + gk] : 0.f;
      int gn = n0 + m;
      Bs[k][m] = (gn < N && gk < K) ? B[(size_t)gn*ldb + gk] : 0.f;
    }
    __syncthreads();
    #pragma unroll
    for (int k = 0; k < 16; ++k) {
      float a[4], b[4];
      #pragma unroll
      for (int r = 0; r < 4; ++r) a[r] = As[k][ty*4+r];
      #pragma unroll
      for (int s = 0; s < 4; ++s) b[s] = Bs[k][tx*4+s];
      #pragma unroll
      for (int r = 0; r < 4; ++r)
        #pragma unroll
        for (int s = 0; s < 4; ++s)
          acc[r][s] = fmaf(a[r], b[s], acc[r][s]);
    }
    __syncthreads();
  }
  #pragma unroll
  for (int r = 0; r < 4; ++r) {
    int gm = m0 + ty*4 + r;
    if (gm >= M) continue;
    #pragma unroll
    for (int s = 0; s < 4; ++s) {
      int gn = n0 + tx*4 + s;
      if (gn < N) C[(size_t)gm*ldc + gn] = acc[r][s] + (bias ? bias[gn] : 0.f);
    }
  }
}

// ---------------- patchify: x(B,3,256,256) -> xp(B*N, 768) ----------------
__global__ __launch_bounds__(256) void k_patchify(const float* __restrict__ x,
                                                  float* __restrict__ xp)
{
  int row = blockIdx.x;            // b*256 + n
  int b = row >> 8, n = row & 255;
  int gy = n >> 4, gx = n & 15;
  for (int j = threadIdx.x; j < 768; j += 256) {
    int c = j >> 8, r = j & 255, py = r >> 4, px = r & 15;
    xp[(size_t)row*768 + j] =
        x[(((size_t)b*3 + c)*256 + gy*16 + py)*256 + gx*16 + px];
  }
}

// ---------------- h += pos_embed (broadcast over batch) ----------------
__global__ void k_addpos(float* __restrict__ h, const float* __restrict__ pos)
{
  int i = blockIdx.x*256 + threadIdx.x;     // 4096*1024
  if (i >= 4096*1024) return;
  int row = i >> 10; int n = row & 255; int d = i & 1023;
  h[i] += pos[n*1024 + d];
}

// ---------------- timestep raw embedding (16x256) ----------------
__global__ void k_temb(const float* __restrict__ t, float* __restrict__ temb)
{
  int i = blockIdx.x*256 + threadIdx.x;     // 16*128
  if (i >= 16*128) return;
  int b = i >> 7, j = i & 127;
  float fr = expf(-logf(10000.f) * (float)j / 128.f);
  float a = t[b] * fr;
  temb[b*256 + j]       = cosf(a);
  temb[b*256 + 128 + j] = sinf(a);
}

__global__ void k_silu(float* __restrict__ v, int n)
{
  int i = blockIdx.x*256 + threadIdx.x;
  if (i < n) v[i] = silu_f(v[i]);
}

// c += y_table[y]; silu_c = silu(c)
__global__ void k_ysilu(float* __restrict__ c, const float* __restrict__ ytab,
                        const int* __restrict__ y, float* __restrict__ sc)
{
  int i = blockIdx.x*256 + threadIdx.x;     // 16*1024
  if (i >= 16*1024) return;
  int b = i >> 10, d = i & 1023;
  float v = c[i] + ytab[(size_t)y[b]*1024 + d];
  c[i] = v;
  sc[i] = silu_f(v);
}

// ---------------- rope tables (N=256, HD=64) ----------------
__global__ void k_ropetab(float* __restrict__ ct, float* __restrict__ st)
{
  int i = blockIdx.x*256 + threadIdx.x;     // 256*64
  if (i >= 256*64) return;
  int n = i >> 6, d = i & 63;
  int gy = n >> 4, gx = n & 15;
  int g = (d < 32) ? gy : gx;
  int j = (d & 31) >> 1;
  float fr = powf(10000.f, -(float)(2*j)/32.f);
  float a = (float)g * fr;
  ct[i] = cosf(a); st[i] = sinf(a);
}

// ---------------- RMSNorm + adaLN modulate: out = rms(h)*w*(1+scale)+shift ----------------
__global__ __launch_bounds__(256) void k_rmsmod(
    const float* __restrict__ h, const float* __restrict__ w,
    const float* __restrict__ ada, int ald, int soff, int scoff,
    float* __restrict__ out)
{
  int row = blockIdx.x; int b = row >> 8;
  int tid = threadIdx.x;
  const float* hr = h + (size_t)row*1024;
  float v[4]; float ss = 0.f;
  #pragma unroll
  for (int r = 0; r < 4; ++r) { v[r] = hr[tid + 256*r]; ss += v[r]*v[r]; }
  ss = wsum(ss);
  __shared__ float red[4];
  if ((tid & 63) == 0) red[tid >> 6] = ss;
  __syncthreads();
  float inv = rsqrtf((red[0]+red[1]+red[2]+red[3]) * (1.f/1024.f) + 1e-6f);
  const float* sh  = ada + (size_t)b*ald + soff;
  const float* sca = ada + (size_t)b*ald + scoff;
  float* orow = out + (size_t)row*1024;
  #pragma unroll
  for (int r = 0; r < 4; ++r) {
    int d = tid + 256*r;
    orow[d] = v[r]*inv*w[d]*(1.f + sca[d]) + sh[d];
  }
}

// ---------------- q/k rms + rope + rearrange to (B,H,N,HD); v rearrange ----------------
__global__ __launch_bounds__(64) void k_qkrope(
    const float* __restrict__ qkv, const float* __restrict__ qnw,
    const float* __restrict__ knw, const float* __restrict__ ct,
    const float* __restrict__ st,
    float* __restrict__ qr, float* __restrict__ kr, float* __restrict__ vr)
{
  int idx = blockIdx.x;                 // ((b*16+h)*256 + n)
  int n = idx & 255, h = (idx >> 8) & 15, b = idx >> 12;
  int d = threadIdx.x;
  size_t base = ((size_t)(b*256 + n))*3072 + h*64 + d;
  float q = qkv[base];
  float k = qkv[base + 1024];
  float v = qkv[base + 2048];
  float qs = wsum(q*q);
  float ks = wsum(k*k);
  float qn = q * rsqrtf(qs*(1.f/64.f) + 1e-6f) * qnw[d];
  float kn = k * rsqrtf(ks*(1.f/64.f) + 1e-6f) * knw[d];
  float qp = __shfl_xor(qn, 1);
  float kp = __shfl_xor(kn, 1);
  float c = ct[n*64 + d], s = st[n*64 + d];
  float sgn = (d & 1) ? 1.f : -1.f;
  size_t ob = ((size_t)idx)*64 + d;
  qr[ob] = qn*c + sgn*qp*s;
  kr[ob] = kn*c + sgn*kp*s;
  vr[ob] = v;
}

// ---------------- fused attention per (b,h): K/V staged in LDS ----------------
__global__ __launch_bounds__(256) void k_attn(
    const float* __restrict__ qr, const float* __restrict__ kr,
    const float* __restrict__ vr, float* __restrict__ om)
{
  __shared__ float ks[256*65];   // padded: score loop reads column-wise
  __shared__ float vs[256*64];   // unpadded: PV reads are consecutive-d per lane
  __shared__ float qs[64];
  __shared__ float sc[256];
  __shared__ float pv[4][64];
  __shared__ float red[4];
  int tid = threadIdx.x;
  int bh = blockIdx.x; int b = bh >> 4, hh = bh & 15;
  const float* kb = kr + (size_t)bh*256*64;
  const float* vb = vr + (size_t)bh*256*64;
  for (int i = tid; i < 256*64; i += 256) {
    int m = i >> 6, d = i & 63;
    ks[m*65 + d] = kb[i];
    vs[i] = vb[i];
  }
  __syncthreads();
  const float isq = 0.125f;   // 1/sqrt(64)
  for (int n = 0; n < 256; ++n) {
    if (tid < 64) qs[tid] = qr[(size_t)bh*256*64 + (size_t)n*64 + tid];
    __syncthreads();
    // scores: thread = key index m
    float s = 0.f;
    const float* krow = &ks[tid*65];
    #pragma unroll 8
    for (int d = 0; d < 64; ++d) s = fmaf(qs[d], krow[d], s);
    s *= isq;
    // block max
    float mx = wmaxr(s);
    if ((tid & 63) == 0) red[tid >> 6] = mx;
    __syncthreads();
    mx = fmaxf(fmaxf(red[0], red[1]), fmaxf(red[2], red[3]));
    float p = expf(s - mx);
    float smw = wsum(p);
    __syncthreads();
    if ((tid & 63) == 0) red[tid >> 6] = smw;
    __syncthreads();
    float denom = red[0]+red[1]+red[2]+red[3];
    sc[tid] = p / denom;
    __syncthreads();
    // PV: 4 m-groups x 64 d-lanes
    int d = tid & 63, g = tid >> 6;
    float acc = 0.f;
    #pragma unroll 8
    for (int m = g*64; m < g*64 + 64; ++m) acc = fmaf(sc[m], vs[m*64 + d], acc);
    pv[g][d] = acc;
    __syncthreads();
    if (tid < 64) {
      om[((size_t)(b*256 + n))*1024 + hh*64 + tid] =
          pv[0][tid] + pv[1][tid] + pv[2][tid] + pv[3][tid];
    }
    __syncthreads();
  }
}

// ---------------- gated residual: h += gate * po ----------------
__global__ __launch_bounds__(256) void k_resgate(
    float* __restrict__ h, const float* __restrict__ po,
    const float* __restrict__ ada, int goff)
{
  int row = blockIdx.x; int b = row >> 8;
  size_t base = (size_t)row*1024;
  const float* g = ada + (size_t)b*6144 + goff;
  for (int d = threadIdx.x; d < 1024; d += 256)
    h[base + d] += g[d] * po[base + d];
}

// ---------------- swiglu: hg = silu(x1)*x2 ----------------
__global__ __launch_bounds__(256) void k_swiglu(
    const float* __restrict__ x12, float* __restrict__ hg)
{
  int row = blockIdx.x;
  const float* r = x12 + (size_t)row*5460;
  float* o = hg + (size_t)row*2730;
  for (int j = threadIdx.x; j < 2730; j += 256) {
    float a = r[j], bb = r[j + 2730];
    o[j] = silu_f(a) * bb;
  }
}

// ---------------- unpatchify: tok(B*N,768) -> out(B,3,256,256) ----------------
__global__ void k_unpatch(const float* __restrict__ tok, float* __restrict__ out)
{
  int i = blockIdx.x*256 + threadIdx.x;   // 16*3*256*256
  if (i >= 16*3*256*256) return;
  int ix = i & 255, iy = (i >> 8) & 255;
  int bc = i >> 16; int b = bc / 3, c = bc % 3;
  int gy = iy >> 4, py = iy & 15, gx = ix >> 4, px = ix & 15;
  out[i] = tok[((size_t)(b*256 + gy*16 + gx))*768 + (py*16 + px)*3 + c];
}

// ---------------- host orchestration ----------------
static inline void launch_gemm(const float* A, const float* B, const float* bias,
                               float* C, int M, int N, int K,
                               int lda, int ldb, int ldc, hipStream_t s)
{
  dim3 g(CDIV(N,64), CDIV(M,64));
  gemm_nt<<<g, 256, 0, s>>>(A, B, bias, C, M, N, K, lda, ldb, ldc);
}

extern "C" void kernel_launch(void* const* d_in, const int* in_sizes, int n_in,
                              void* d_out, int out_size, void* d_ws, size_t ws_size,
                              hipStream_t stream)
{
  const float* x    = (const float*)d_in[0];
  const float* t    = (const float*)d_in[1];
  const int*   y    = (const int*)  d_in[2];
  const float* pos  = (const float*)d_in[3];
  const float* pw1  = (const float*)d_in[4];
  const float* pw2  = (const float*)d_in[5];
  const float* pb2  = (const float*)d_in[6];
  const float* tw1  = (const float*)d_in[7];
  const float* tb1  = (const float*)d_in[8];
  const float* tw2  = (const float*)d_in[9];
  const float* tb2  = (const float*)d_in[10];
  const float* ytab = (const float*)d_in[11];
  const float* n1w  = (const float*)d_in[12];
  const float* qkvw = (const float*)d_in[13];
  const float* qkvb = (const float*)d_in[14];
  const float* qnw  = (const float*)d_in[15];
  const float* knw  = (const float*)d_in[16];
  const float* pjw  = (const float*)d_in[17];
  const float* pjb  = (const float*)d_in[18];
  const float* n2w  = (const float*)d_in[19];
  const float* w12w = (const float*)d_in[20];
  const float* w12b = (const float*)d_in[21];
  const float* w3w  = (const float*)d_in[22];
  const float* w3b  = (const float*)d_in[23];
  const float* adw  = (const float*)d_in[24];
  const float* adb  = (const float*)d_in[25];
  const float* fnw  = (const float*)d_in[26];
  const float* flw  = (const float*)d_in[27];
  const float* flb  = (const float*)d_in[28];
  const float* faw  = (const float*)d_in[29];
  const float* fab  = (const float*)d_in[30];

  float* ws = (float*)d_ws;
  float* h     = ws;                       // 4096*1024
  float* bufA  = h     + 4194304;          // 4096*1024   (xm / proj-out)
  float* bufB  = bufA  + 4194304;          // 4096*5460   (qkv / attn-out / x12)
  float* qr    = bufB  + 22364160;         // 4096*1024
  float* kr    = qr    + 4194304;
  float* vr    = kr    + 4194304;
  float* hg    = vr    + 4194304;          // 4096*2730   (also xp, h1 at start)
  float* ada   = hg    + 11182080;         // 16*6144
  float* tembr = ada   + 98304;            // 16*256
  float* tembh = tembr + 4096;             // 16*1024
  float* cbuf  = tembh + 16384;            // 16*1024
  float* scb   = cbuf  + 16384;            // 16*1024 (silu(c))
  float* fda   = scb   + 16384;            // 16*2048
  float* cost  = fda   + 32768;            // 256*64
  float* sint  = cost  + 16384;            // 256*64
  float* xp    = hg;                       // 4096*768 (pre-layer only)
  float* h1    = hg + 3145728;             // 4096*128 (pre-layer only)
  float* tok   = qr;                       // 4096*768 (post-layer only)

  // ---- patch embed ----
  k_patchify<<<4096, 256, 0, stream>>>(x, xp);
  launch_gemm(xp, pw1, nullptr, h1, 4096, 128, 768, 768, 768, 128, stream);
  launch_gemm(h1, pw2, pb2, h, 4096, 1024, 128, 128, 128, 1024, stream);
  k_addpos<<<16384, 256, 0, stream>>>(h, pos);

  // ---- timestep + class embed ----
  k_temb<<<8, 256, 0, stream>>>(t, tembr);
  launch_gemm(tembr, tw1, tb1, tembh, 16, 1024, 256, 256, 256, 1024, stream);
  k_silu<<<64, 256, 0, stream>>>(tembh, 16384);
  launch_gemm(tembh, tw2, tb2, cbuf, 16, 1024, 1024, 1024, 1024, 1024, stream);
  k_ysilu<<<64, 256, 0, stream>>>(cbuf, ytab, y, scb);
  k_ropetab<<<64, 256, 0, stream>>>(cost, sint);

  // ---- transformer layers ----
  for (int i = 0; i < 12; ++i) {
    const float* adwi = adw + (size_t)i*6144*1024;
    launch_gemm(scb, adwi, adb + (size_t)i*6144, ada, 16, 6144, 1024,
                1024, 1024, 6144, stream);
    k_rmsmod<<<4096, 256, 0, stream>>>(h, n1w + i*1024, ada, 6144, 0, 1024, bufA);
    launch_gemm(bufA, qkvw + (size_t)i*3072*1024, qkvb + (size_t)i*3072, bufB,
                4096, 3072, 1024, 1024, 1024, 3072, stream);
    k_qkrope<<<65536, 64, 0, stream>>>(bufB, qnw + i*64, knw + i*64,
                                       cost, sint, qr, kr, vr);
    k_attn<<<256, 256, 0, stream>>>(qr, kr, vr, bufB);
    launch_gemm(bufB, pjw + (size_t)i*1024*1024, pjb + (size_t)i*1024, bufA,
                4096, 1024, 1024, 1024, 1024, 1024, stream);
    k_resgate<<<4096, 256, 0, stream>>>(h, bufA, ada, 2048);
    k_rmsmod<<<4096, 256, 0, stream>>>(h, n2w + i*1024, ada, 6144, 3072, 4096, bufA);
    launch_gemm(bufA, w12w + (size_t)i*5460*1024, w12b + (size_t)i*5460, bufB,
                4096, 5460, 1024, 1024, 1024, 5460, stream);
    k_swiglu<<<4096, 256, 0, stream>>>(bufB, hg);
    launch_gemm(hg, w3w + (size_t)i*1024*2730, w3b + (size_t)i*1024, bufA,
                4096, 1024, 2730, 2730, 2730, 1024, stream);
    k_resgate<<<4096, 256, 0, stream>>>(h, bufA, ada, 5120);
  }

  // ---- final layer ----
  launch_gemm(scb, faw, fab, fda, 16, 2048, 1024, 1024, 1024, 2048, stream);
  k_rmsmod<<<4096, 256, 0, stream>>>(h, fnw, fda, 2048, 0, 1024, bufA);
  launch_gemm(bufA, flw, flb, tok, 4096, 768, 1024, 1024, 1024, 768, stream);
  k_unpatch<<<12288, 256, 0, stream>>>(tok, (float*)d_out);
}